// Round 2
// baseline (3028.680 us; speedup 1.0000x reference)
//
#include <hip/hip_runtime.h>
#include <hip/hip_fp16.h>
#include <stdint.h>

// Problem constants: B=8, L=4096, D=256, K=4096
#define NROWS 32768
#define KC 4096
#define DIM 256
#define TM 64          // rows per block
#define TK 256         // codebook cols per K-tile
#define TD 32          // D-chunk staged in LDS
#define NKT (KC / TK)  // 16
#define NDT (DIM / TD) // 8
#define NBLK (NROWS / TM) // 512

// Output layout (flat fp32): z_q_ste [N*D], indices [N], vq, ccl, sel
#define OUT_IDX (NROWS * DIM)
#define OUT_SCAL (OUT_IDX + NROWS)

// Workspace layout (bytes)
#define WS_CNORM 0
#define WS_AVGP 16384
#define WS_LOSS 32768
#define WS_ZNORM 33024                        // 32768 floats = 128 KB
#define WS_SCORES 164096                      // 256-aligned
#define SCORES_BYTES ((size_t)NROWS * KC * 2) // fp16 scores, 256 MB

union SharedU {
  struct { float zs[TD][68]; float cs[TD][TK + 4]; } st; // padded vs bank conflicts
  struct { unsigned long long key[TM][32]; float sum[TM][32]; } red;
  float part[8][TK];
  float lred[256];
};

// monotonic float->uint mapping; min over packed (ord<<32)|k gives min value
// with first-index tie-break == np.argmin
__device__ __forceinline__ unsigned ford(float f) {
  unsigned u = __float_as_uint(f);
  return (u & 0x80000000u) ? ~u : (u | 0x80000000u);
}

// numpy pairwise-sum of x[i]^2 for n=256, matching np.sum(x**2) bitwise:
// two halves of 128; each half: 8 accumulator chains, combined
// ((r0+r1)+(r2+r3))+((r4+r5)+(r6+r7)); total = half0 + half1.
// Squares are rounded separately (np computes x**2 array first) - no FMA.
__device__ __forceinline__ float np_rownorm256(const float* __restrict__ p) {
  float h[2];
  #pragma unroll
  for (int half = 0; half < 2; ++half) {
    const float* b = p + half * 128;
    float r[8];
    #pragma unroll
    for (int j = 0; j < 8; ++j) {
      float v = b[j];
      r[j] = __fmul_rn(v, v);
    }
    for (int i = 8; i < 128; i += 8) {
      #pragma unroll
      for (int j = 0; j < 8; ++j) {
        float v = b[i + j];
        r[j] = __fadd_rn(r[j], __fmul_rn(v, v));
      }
    }
    h[half] = __fadd_rn(
        __fadd_rn(__fadd_rn(r[0], r[1]), __fadd_rn(r[2], r[3])),
        __fadd_rn(__fadd_rn(r[4], r[5]), __fadd_rn(r[6], r[7])));
  }
  return __fadd_rn(h[0], h[1]);
}

__global__ void k_rownorm(const float* __restrict__ x, float* __restrict__ out,
                          int nrows) {
  int r = blockIdx.x * 256 + threadIdx.x;
  if (r < nrows) out[r] = np_rownorm256(x + (size_t)r * DIM);
}

// One 64x256 tile: acc[i][j] = dot(z[row0+trow*8+i], cb[k0+tcol*8+j]).
// Accumulation is a single sequential fmaf chain over d=0..255 (dt-major,
// d-minor) to match BLAS sgemm micro-kernel k-accumulation.
__device__ __forceinline__ void gemm_tile(const float* __restrict__ z,
                                          const float* __restrict__ cbw,
                                          SharedU& sh, int row0, int k0, int t,
                                          int trow, int tcol, float acc[8][8]) {
  #pragma unroll
  for (int i = 0; i < 8; ++i)
    #pragma unroll
    for (int j = 0; j < 8; ++j) acc[i][j] = 0.f;
  for (int dt = 0; dt < NDT; ++dt) {
    __syncthreads(); // protect LDS (union) before restage
    const int d0 = dt * TD;
    // stage z tile transposed: zs[d][row]
    #pragma unroll
    for (int s = 0; s < 2; ++s) {
      int idx = t + 256 * s;
      int row = idx >> 3, dg = idx & 7;
      float4 v = *(const float4*)(z + (size_t)(row0 + row) * DIM + d0 + dg * 4);
      sh.st.zs[dg * 4 + 0][row] = v.x;
      sh.st.zs[dg * 4 + 1][row] = v.y;
      sh.st.zs[dg * 4 + 2][row] = v.z;
      sh.st.zs[dg * 4 + 3][row] = v.w;
    }
    // stage codebook tile transposed: cs[d][k]
    #pragma unroll
    for (int s = 0; s < 8; ++s) {
      int idx = t + 256 * s;
      int kk = idx >> 3, dg = idx & 7;
      float4 v = *(const float4*)(cbw + (size_t)(k0 + kk) * DIM + d0 + dg * 4);
      sh.st.cs[dg * 4 + 0][kk] = v.x;
      sh.st.cs[dg * 4 + 1][kk] = v.y;
      sh.st.cs[dg * 4 + 2][kk] = v.z;
      sh.st.cs[dg * 4 + 3][kk] = v.w;
    }
    __syncthreads();
    #pragma unroll
    for (int d = 0; d < TD; ++d) {
      float4 za = *(const float4*)&sh.st.zs[d][trow * 8];
      float4 zb = *(const float4*)&sh.st.zs[d][trow * 8 + 4];
      float4 ca = *(const float4*)&sh.st.cs[d][tcol * 8];
      float4 cb4 = *(const float4*)&sh.st.cs[d][tcol * 8 + 4];
      float zr[8] = {za.x, za.y, za.z, za.w, zb.x, zb.y, zb.z, zb.w};
      float cr[8] = {ca.x, ca.y, ca.z, ca.w, cb4.x, cb4.y, cb4.z, cb4.w};
      #pragma unroll
      for (int i = 0; i < 8; ++i)
        #pragma unroll
        for (int j = 0; j < 8; ++j)
          acc[i][j] = __builtin_fmaf(zr[i], cr[j], acc[i][j]);
    }
  }
}

__global__ __launch_bounds__(256) void k_main(
    const float* __restrict__ z, const float* __restrict__ cbw,
    const float* __restrict__ cnorm, const float* __restrict__ znorm,
    float* __restrict__ out, float* __restrict__ avgp,
    double* __restrict__ losssum, __half* __restrict__ scoresH, int useStore) {
  __shared__ SharedU sh;
  __shared__ float invR[TM];
  __shared__ int idxr[TM];
  const int t = threadIdx.x;
  const int trow = t >> 5, tcol = t & 31;
  const int row0 = blockIdx.x * TM;

  unsigned long long mkey[8];
  float esum[8];
  float rnr[8];
  #pragma unroll
  for (int i = 0; i < 8; ++i) {
    mkey[i] = ~0ULL;
    esum[i] = 0.f;
    rnr[i] = znorm[row0 + trow * 8 + i];
  }

  // ---------- Phase 1: scores, argmin (np-quantized), softmax row-sums ------
  for (int kt = 0; kt < NKT; ++kt) {
    const int k0 = kt * TK;
    float acc[8][8];
    gemm_tile(z, cbw, sh, row0, k0, t, trow, tcol, acc);
    float cn[8];
    #pragma unroll
    for (int j = 0; j < 8; ++j) cn[j] = cnorm[k0 + tcol * 8 + j];
    #pragma unroll
    for (int i = 0; i < 8; ++i) {
      float st8[8];
      #pragma unroll
      for (int j = 0; j < 8; ++j) {
        float u = __fmul_rn(2.f, acc[i][j]);          // exact
        float st = __fsub_rn(cn[j], u);               // softmax score (shifted)
        st8[j] = st;
        esum[i] += __expf(-st);
        // np-exact: d2 = fl(fl(rn + cn) - fl(2*mm))  -> argmin on this
        float d2 = __fsub_rn(__fadd_rn(rnr[i], cn[j]), u);
        unsigned long long key =
            ((unsigned long long)ford(d2) << 32) | (unsigned)(k0 + tcol * 8 + j);
        if (key < mkey[i]) mkey[i] = key;
      }
      if (useStore) {
        __half hb[8];
        #pragma unroll
        for (int j = 0; j < 8; ++j) hb[j] = __float2half(st8[j]);
        *(int4*)(scoresH + (size_t)(row0 + trow * 8 + i) * KC + k0 + tcol * 8) =
            *(const int4*)hb;
      }
    }
  }

  // reduce argmin / rowsum across the 32 tcol threads per row
  __syncthreads();
  #pragma unroll
  for (int i = 0; i < 8; ++i) {
    sh.red.key[trow * 8 + i][tcol] = mkey[i];
    sh.red.sum[trow * 8 + i][tcol] = esum[i];
  }
  __syncthreads();
  if (t < TM) {
    unsigned long long kb = ~0ULL;
    float rs = 0.f;
    for (int c = 0; c < 32; ++c) {
      unsigned long long kk = sh.red.key[t][c];
      if (kk < kb) kb = kk;
      rs += sh.red.sum[t][c];
    }
    int idx = (int)(kb & 0xFFFFFFFFULL);
    idxr[t] = idx;
    invR[t] = 1.0f / rs;
    out[OUT_IDX + row0 + t] = (float)idx;
  }
  __syncthreads();

  // ---------- z_q gather, STE output, loss partial ----------
  float lacc = 0.f;
  for (int r = 0; r < TM; ++r) {
    int idx = idxr[r];
    float zq = cbw[(size_t)idx * DIM + t];
    float zv = z[(size_t)(row0 + r) * DIM + t];
    float df = __fsub_rn(zq, zv);
    out[(size_t)(row0 + r) * DIM + t] = __fadd_rn(zv, df); // z + (z_q - z)
    lacc += df * df;
  }
  __syncthreads();
  sh.lred[t] = lacc;
  __syncthreads();
  #pragma unroll
  for (int sft = 128; sft > 0; sft >>= 1) {
    if (t < sft) sh.lred[t] += sh.lred[t + sft];
    __syncthreads();
  }
  if (t == 0) atomicAdd(losssum, (double)sh.lred[0]);

  // ---------- Phase 2: avg_probs accumulation ----------
  for (int kt = 0; kt < NKT; ++kt) {
    const int k0 = kt * TK;
    float pc[8];
    #pragma unroll
    for (int j = 0; j < 8; ++j) pc[j] = 0.f;
    if (useStore) {
      #pragma unroll
      for (int i = 0; i < 8; ++i) {
        const int r = trow * 8 + i;
        int4 hv = *(const int4*)(scoresH + (size_t)(row0 + r) * KC + k0 + tcol * 8);
        const __half* hp = (const __half*)&hv;
        float ivr = invR[r];
        #pragma unroll
        for (int j = 0; j < 8; ++j)
          pc[j] += __expf(-__half2float(hp[j])) * ivr;
      }
    } else {
      float acc[8][8];
      gemm_tile(z, cbw, sh, row0, k0, t, trow, tcol, acc);
      float cn[8];
      #pragma unroll
      for (int j = 0; j < 8; ++j) cn[j] = cnorm[k0 + tcol * 8 + j];
      #pragma unroll
      for (int i = 0; i < 8; ++i) {
        float ivr = invR[trow * 8 + i];
        #pragma unroll
        for (int j = 0; j < 8; ++j) {
          float st = __fsub_rn(cn[j], __fmul_rn(2.f, acc[i][j]));
          pc[j] += __expf(-st) * ivr;
        }
      }
    }
    __syncthreads(); // protect part (union) vs previous consumers
    #pragma unroll
    for (int j = 0; j < 8; ++j) sh.part[trow][tcol * 8 + j] = pc[j];
    __syncthreads();
    {
      float csum = 0.f;
      #pragma unroll
      for (int g = 0; g < 8; ++g) csum += sh.part[g][t];
      atomicAdd(&avgp[k0 + t], csum);
    }
  }
}

__global__ void k_final(const float* __restrict__ avgp,
                        const double* __restrict__ losssum,
                        float* __restrict__ out) {
  const int t = threadIdx.x;
  double part = 0.0;
  for (int k = t; k < KC; k += 256) {
    double a = (double)avgp[k] / (double)NROWS;
    part += a * log(a + 1e-10);
  }
  __shared__ double sd[256];
  sd[t] = part;
  __syncthreads();
  for (int sft = 128; sft > 0; sft >>= 1) {
    if (t < sft) sd[t] += sd[t + sft];
    __syncthreads();
  }
  if (t == 0) {
    double H = -sd[0]; // entropy
    double mse = losssum[0] / (double)((size_t)NROWS * DIM);
    double ccl = 1.25 * mse;        // codebook + 0.25*commitment (same value fwd)
    double sel = -0.1 * H;          // ENTROPY_WEIGHT * (-entropy)
    out[OUT_SCAL + 0] = (float)(ccl + sel); // vq_loss
    out[OUT_SCAL + 1] = (float)ccl;
    out[OUT_SCAL + 2] = (float)sel;
  }
}

extern "C" void kernel_launch(void* const* d_in, const int* in_sizes, int n_in,
                              void* d_out, int out_size, void* d_ws, size_t ws_size,
                              hipStream_t stream) {
  const float* z = (const float*)d_in[0];
  const float* cbw = (const float*)d_in[1];
  float* out = (float*)d_out;
  char* ws = (char*)d_ws;
  float* cnorm = (float*)(ws + WS_CNORM);
  float* avgp = (float*)(ws + WS_AVGP);
  double* losssum = (double*)(ws + WS_LOSS);
  float* znorm = (float*)(ws + WS_ZNORM);
  __half* scoresH = (__half*)(ws + WS_SCORES);
  const int useStore = (ws_size >= (size_t)WS_SCORES + SCORES_BYTES) ? 1 : 0;

  hipMemsetAsync(ws + WS_AVGP, 0, KC * 4, stream);
  hipMemsetAsync(ws + WS_LOSS, 0, 8, stream);
  k_rownorm<<<(KC + 255) / 256, 256, 0, stream>>>(cbw, cnorm, KC);
  k_rownorm<<<(NROWS + 255) / 256, 256, 0, stream>>>(z, znorm, NROWS);
  k_main<<<NBLK, 256, 0, stream>>>(z, cbw, cnorm, znorm, out, avgp, losssum,
                                   scoresH, useStore);
  k_final<<<1, 256, 0, stream>>>(avgp, losssum, out);
}

// Round 3
// 756.042 us; speedup vs baseline: 4.0060x; 4.0060x over previous
//
#include <hip/hip_runtime.h>
#include <stdint.h>

// Problem: B=8, L=4096, D=256, K=4096
#define NROWS 32768
#define KC 4096
#define DIM 256
#define BM 128            // rows per block
#define BN 128            // codes per k-tile
#define NKT (KC / BN)     // 32
#define NCH 8             // d-chunks of 32 per k-tile
#define CAP 24
#define MARGIN 8e-5f      // 2x quantization half-ulp(~256) + approx err, w/ slack

#define OUT_IDX (NROWS * DIM)
#define OUT_SCAL (OUT_IDX + NROWS)

#define WS_CNORM 0
#define WS_AVGP 16384
#define WS_LOSS 32768
#define WS_ZNORM 33024    // 128 KB of row norms; ws use ends at ~164 KB

typedef __bf16 bf8 __attribute__((ext_vector_type(8)));
typedef float f16v __attribute__((ext_vector_type(16)));

union Bf8U { unsigned short s[8]; bf8 v; };
struct Chunk { float4 q[4]; };   // 16 floats

// monotonic float<->uint order maps (argmin with first-index tie-break)
__device__ __forceinline__ unsigned ford(float f) {
  unsigned u = __float_as_uint(f);
  return (u & 0x80000000u) ? ~u : (u | 0x80000000u);
}
__device__ __forceinline__ float unford(unsigned u) {
  return __uint_as_float((u & 0x80000000u) ? (u ^ 0x80000000u) : ~u);
}
__device__ __forceinline__ unsigned short bfr(float f) {  // fp32 -> bf16 RNE
  unsigned u = __float_as_uint(f);
  return (unsigned short)((u + 0x7FFFu + ((u >> 16) & 1u)) >> 16);
}
__device__ __forceinline__ float bf2f(unsigned short h) {
  return __uint_as_float(((unsigned)h) << 16);
}

// numpy pairwise-sum of x**2 (n=256), bitwise-matching np.sum(x**2) (v2-validated)
__device__ __forceinline__ float np_rownorm256(const float* __restrict__ p) {
  float h[2];
  #pragma unroll
  for (int half = 0; half < 2; ++half) {
    const float* b = p + half * 128;
    float r[8];
    #pragma unroll
    for (int j = 0; j < 8; ++j) { float v = b[j]; r[j] = __fmul_rn(v, v); }
    for (int i = 8; i < 128; i += 8) {
      #pragma unroll
      for (int j = 0; j < 8; ++j) {
        float v = b[i + j];
        r[j] = __fadd_rn(r[j], __fmul_rn(v, v));
      }
    }
    h[half] = __fadd_rn(
        __fadd_rn(__fadd_rn(r[0], r[1]), __fadd_rn(r[2], r[3])),
        __fadd_rn(__fadd_rn(r[4], r[5]), __fadd_rn(r[6], r[7])));
  }
  return __fadd_rn(h[0], h[1]);
}

__global__ void k_rownorm(const float* __restrict__ x, float* __restrict__ out,
                          int nrows) {
  int r = blockIdx.x * 256 + threadIdx.x;
  if (r < nrows) out[r] = np_rownorm256(x + (size_t)r * DIM);
}

// np-bitwise d2 (v2-validated): sequential fmaf chain d=0..255, then
// d2 = fl(fl(rn+cn) - fl(2*mm))
__device__ __forceinline__ float exact_d2(const float* __restrict__ zr,
                                          const float* __restrict__ cr,
                                          float rn, float cn) {
  float mm = 0.f;
  for (int d = 0; d < DIM; d += 4) {
    float4 zv = *(const float4*)(zr + d);
    float4 cv = *(const float4*)(cr + d);
    mm = __builtin_fmaf(zv.x, cv.x, mm);
    mm = __builtin_fmaf(zv.y, cv.y, mm);
    mm = __builtin_fmaf(zv.z, cv.z, mm);
    mm = __builtin_fmaf(zv.w, cv.w, mm);
  }
  return __fsub_rn(__fadd_rn(rn, cn), __fmul_rn(2.f, mm));
}

__global__ __launch_bounds__(256, 1) void k_main(
    const float* __restrict__ z, const float* __restrict__ cbw,
    const float* __restrict__ cnorm, const float* __restrict__ znorm,
    float* __restrict__ out, float* __restrict__ avgp,
    double* __restrict__ losssum) {
  // LDS: B-tiles double-buffered, stride 40 bf16 (80 B: b128 reads uniform 8/bank)
  __shared__ unsigned short sthi[2][BN][40];
  __shared__ unsigned short stlo[2][BN][40];
  __shared__ int cand[BM][CAP];
  __shared__ int ccount[BM];
  __shared__ unsigned rowminU[BM];
  __shared__ unsigned long long rowkey[BM];
  __shared__ float esumL[BM], invR[BM], pcolL[BN], lred[256];
  __shared__ int idxr[BM];

  const int t = threadIdx.x;
  const int lane = t & 63, wv = t >> 6;
  const int ln31 = lane & 31, lh = lane >> 5;
  const int row0 = blockIdx.x * BM;
  const int scode = t >> 1;            // staged code (0..127)
  const int shalf = (t & 1) * 16;      // staged d-offset

  if (t < BM) {
    ccount[t] = 0; rowminU[t] = 0xFFFFFFFFu; esumL[t] = 0.f; rowkey[t] = ~0ULL;
  }

  // ---- A (z rows) register-resident: 16 dsteps x {hi,lo} bf16 fragments ----
  // lane holds z[row0 + wv*32 + ln31][dstep*16 + lh*8 + j]
  bf8 Ah[16], Al[16];
  {
    const float* zp = z + (size_t)(row0 + wv * 32 + ln31) * DIM + lh * 8;
    #pragma unroll
    for (int ds = 0; ds < 16; ++ds) {
      float4 a = *(const float4*)(zp + ds * 16);
      float4 b = *(const float4*)(zp + ds * 16 + 4);
      float v[8] = {a.x, a.y, a.z, a.w, b.x, b.y, b.z, b.w};
      Bf8U H, L;
      #pragma unroll
      for (int j = 0; j < 8; ++j) {
        unsigned short h = bfr(v[j]);
        H.s[j] = h;
        L.s[j] = bfr(v[j] - bf2f(h));
      }
      Ah[ds] = H.v; Al[ds] = L.v;
    }
  }
  __syncthreads();

  float rmF[16], es[16];
  #pragma unroll
  for (int i = 0; i < 16; ++i) { rmF[i] = 3.4e38f; es[i] = 0.f; }

  // =================== Phase 1: split-bf16 3-MFMA sweep ===================
  for (int kt = 0; kt < NKT; ++kt) {
    const int k0 = kt * BN;
    const float* cbase = cbw + (size_t)(k0 + scode) * DIM + shalf;
    f16v acc[4];
    #pragma unroll
    for (int n = 0; n < 4; ++n)
      #pragma unroll
      for (int r = 0; r < 16; ++r) acc[n][r] = 0.f;

    Chunk pr[2];
    #pragma unroll
    for (int i = 0; i < 4; ++i) pr[0].q[i] = *(const float4*)(cbase + i * 4);
    #pragma unroll
    for (int i = 0; i < 4; ++i) pr[1].q[i] = *(const float4*)(cbase + 32 + i * 4);
    { // write chunk 0 -> buf 0
      const float* p = (const float*)&pr[0];
      Bf8U H0, H1, L0, L1;
      #pragma unroll
      for (int j = 0; j < 8; ++j) {
        unsigned short h = bfr(p[j]);     H0.s[j] = h; L0.s[j] = bfr(p[j] - bf2f(h));
        unsigned short g = bfr(p[j + 8]); H1.s[j] = g; L1.s[j] = bfr(p[j + 8] - bf2f(g));
      }
      *(bf8*)&sthi[0][scode][shalf] = H0.v; *(bf8*)&sthi[0][scode][shalf + 8] = H1.v;
      *(bf8*)&stlo[0][scode][shalf] = L0.v; *(bf8*)&stlo[0][scode][shalf + 8] = L1.v;
    }
    for (int c = 0; c < NCH; ++c) {
      if (c + 2 < NCH) {
        #pragma unroll
        for (int i = 0; i < 4; ++i)
          pr[c & 1].q[i] = *(const float4*)(cbase + (c + 2) * 32 + i * 4);
      }
      __syncthreads();   // everyone done computing from buf[(c+1)&1]'s old data
      if (c + 1 < NCH) { // write chunk c+1 -> buf[(c+1)&1]
        const float* p = (const float*)&pr[(c + 1) & 1];
        int b = (c + 1) & 1;
        Bf8U H0, H1, L0, L1;
        #pragma unroll
        for (int j = 0; j < 8; ++j) {
          unsigned short h = bfr(p[j]);     H0.s[j] = h; L0.s[j] = bfr(p[j] - bf2f(h));
          unsigned short g = bfr(p[j + 8]); H1.s[j] = g; L1.s[j] = bfr(p[j + 8] - bf2f(g));
        }
        *(bf8*)&sthi[b][scode][shalf] = H0.v; *(bf8*)&sthi[b][scode][shalf + 8] = H1.v;
        *(bf8*)&stlo[b][scode][shalf] = L0.v; *(bf8*)&stlo[b][scode][shalf + 8] = L1.v;
      }
      // compute on buf[c&1]  (reads were ordered by the barrier above)
      #pragma unroll
      for (int ds = 0; ds < 2; ++ds) {
        const int dg = c * 2 + ds;
        #pragma unroll
        for (int n = 0; n < 4; ++n) {
          bf8 Bh = *(bf8*)&sthi[c & 1][n * 32 + ln31][lh * 8 + ds * 16];
          bf8 Bl = *(bf8*)&stlo[c & 1][n * 32 + ln31][lh * 8 + ds * 16];
          acc[n] = __builtin_amdgcn_mfma_f32_32x32x16_bf16(Ah[dg], Bh, acc[n], 0, 0, 0);
          acc[n] = __builtin_amdgcn_mfma_f32_32x32x16_bf16(Al[dg], Bh, acc[n], 0, 0, 0);
          acc[n] = __builtin_amdgcn_mfma_f32_32x32x16_bf16(Ah[dg], Bl, acc[n], 0, 0, 0);
        }
      }
    }
    // ---- scoring: st = cn - 2*acc (shift-invariant score) ----
    #pragma unroll
    for (int n = 0; n < 4; ++n) {
      float cn = cnorm[k0 + n * 32 + ln31];
      #pragma unroll
      for (int r = 0; r < 16; ++r)
        acc[n][r] = __fsub_rn(cn, __fmul_rn(2.f, acc[n][r]));
    }
    if (kt == 0) { // prime rowminU so candidate insertion volume stays tiny
      #pragma unroll
      for (int r = 0; r < 16; ++r) {
        float m = rmF[r];
        #pragma unroll
        for (int n = 0; n < 4; ++n) m = fminf(m, acc[n][r]);
        rmF[r] = m;
        int row = (r & 3) + 8 * (r >> 2) + 4 * lh + 32 * wv;
        atomicMin(&rowminU[row], ford(m));
      }
      __syncthreads();
    }
    #pragma unroll
    for (int r = 0; r < 16; ++r) {
      int row = (r & 3) + 8 * (r >> 2) + 4 * lh + 32 * wv;
      rmF[r] = fminf(rmF[r], unford(rowminU[row]));
      float e = es[r];
      #pragma unroll
      for (int n = 0; n < 4; ++n) {
        float sc = acc[n][r];
        e += __expf(-sc);
        if (sc < rmF[r]) { rmF[r] = sc; atomicMin(&rowminU[row], ford(sc)); }
        if (sc <= rmF[r] + MARGIN) {
          int slot = atomicAdd(&ccount[row], 1);
          if (slot < CAP) cand[row][slot] = k0 + n * 32 + ln31;
        }
      }
      es[r] = e;
    }
  }

  // ---- row softmax sums ----
  #pragma unroll
  for (int r = 0; r < 16; ++r) {
    int row = (r & 3) + 8 * (r >> 2) + 4 * lh + 32 * wv;
    atomicAdd(&esumL[row], es[r]);
  }
  __syncthreads();
  if (t < BM) invR[t] = 1.0f / esumL[t];
  __syncthreads();

  // ---- exact np-bitwise rescore of candidates -> argmin ----
  {
    int r = t & 127, half = t >> 7;
    int cnt = ccount[r];
    const float* zr = z + (size_t)(row0 + r) * DIM;
    float rn = znorm[row0 + r];
    if (cnt <= CAP) {
      for (int s = half; s < cnt; s += 2) {
        int k = cand[r][s];
        float d2 = exact_d2(zr, cbw + (size_t)k * DIM, rn, cnorm[k]);
        atomicMin(&rowkey[r], (((unsigned long long)ford(d2)) << 32) | (unsigned)k);
      }
    } else { // overflow (astronomically rare): full exact scan, still correct
      for (int k = half; k < KC; k += 2) {
        float d2 = exact_d2(zr, cbw + (size_t)k * DIM, rn, cnorm[k]);
        atomicMin(&rowkey[r], (((unsigned long long)ford(d2)) << 32) | (unsigned)k);
      }
    }
  }
  __syncthreads();
  if (t < BM) {
    int idx = (int)(rowkey[t] & 0xFFFFFFFFULL);
    idxr[t] = idx;
    out[OUT_IDX + row0 + t] = (float)idx;
  }
  __syncthreads();

  // ---- z_q gather, STE output, loss partial ----
  float lacc = 0.f;
  for (int r = 0; r < BM; ++r) {
    int idx = idxr[r];
    float zq = cbw[(size_t)idx * DIM + t];
    float zv = z[(size_t)(row0 + r) * DIM + t];
    float df = __fsub_rn(zq, zv);
    out[(size_t)(row0 + r) * DIM + t] = __fadd_rn(zv, df);
    lacc += df * df;
  }
  lred[t] = lacc;
  __syncthreads();
  #pragma unroll
  for (int s = 128; s > 0; s >>= 1) {
    if (t < s) lred[t] += lred[t + s];
    __syncthreads();
  }
  if (t == 0) atomicAdd(losssum, (double)lred[0]);

  // =================== Phase 2: hi-only 1-MFMA avg_probs sweep ===================
  float ir[16];
  #pragma unroll
  for (int r = 0; r < 16; ++r)
    ir[r] = invR[(r & 3) + 8 * (r >> 2) + 4 * lh + 32 * wv];

  for (int kt = 0; kt < NKT; ++kt) {
    const int k0 = kt * BN;
    const float* cbase = cbw + (size_t)(k0 + scode) * DIM + shalf;
    f16v acc[4];
    #pragma unroll
    for (int n = 0; n < 4; ++n)
      #pragma unroll
      for (int r = 0; r < 16; ++r) acc[n][r] = 0.f;
    if (t < BN) pcolL[t] = 0.f;

    Chunk pr[2];
    #pragma unroll
    for (int i = 0; i < 4; ++i) pr[0].q[i] = *(const float4*)(cbase + i * 4);
    #pragma unroll
    for (int i = 0; i < 4; ++i) pr[1].q[i] = *(const float4*)(cbase + 32 + i * 4);
    {
      const float* p = (const float*)&pr[0];
      Bf8U H0, H1;
      #pragma unroll
      for (int j = 0; j < 8; ++j) { H0.s[j] = bfr(p[j]); H1.s[j] = bfr(p[j + 8]); }
      *(bf8*)&sthi[0][scode][shalf] = H0.v; *(bf8*)&sthi[0][scode][shalf + 8] = H1.v;
    }
    for (int c = 0; c < NCH; ++c) {
      if (c + 2 < NCH) {
        #pragma unroll
        for (int i = 0; i < 4; ++i)
          pr[c & 1].q[i] = *(const float4*)(cbase + (c + 2) * 32 + i * 4);
      }
      __syncthreads();
      if (c + 1 < NCH) {
        const float* p = (const float*)&pr[(c + 1) & 1];
        int b = (c + 1) & 1;
        Bf8U H0, H1;
        #pragma unroll
        for (int j = 0; j < 8; ++j) { H0.s[j] = bfr(p[j]); H1.s[j] = bfr(p[j + 8]); }
        *(bf8*)&sthi[b][scode][shalf] = H0.v; *(bf8*)&sthi[b][scode][shalf + 8] = H1.v;
      }
      #pragma unroll
      for (int ds = 0; ds < 2; ++ds) {
        const int dg = c * 2 + ds;
        #pragma unroll
        for (int n = 0; n < 4; ++n) {
          bf8 Bh = *(bf8*)&sthi[c & 1][n * 32 + ln31][lh * 8 + ds * 16];
          acc[n] = __builtin_amdgcn_mfma_f32_32x32x16_bf16(Ah[dg], Bh, acc[n], 0, 0, 0);
        }
      }
    }
    #pragma unroll
    for (int n = 0; n < 4; ++n) {
      float cn = cnorm[k0 + n * 32 + ln31];
      float s = 0.f;
      #pragma unroll
      for (int r = 0; r < 16; ++r) {
        float sc = cn - 2.f * acc[n][r];
        s += __expf(-sc) * ir[r];
      }
      s += __shfl_xor(s, 32);     // sum the two row-halves (same col)
      if (lh == 0) atomicAdd(&pcolL[n * 32 + ln31], s);
    }
    __syncthreads();
    if (t < BN) atomicAdd(&avgp[k0 + t], pcolL[t]);
    __syncthreads();
  }
}

__global__ void k_final(const float* __restrict__ avgp,
                        const double* __restrict__ losssum,
                        float* __restrict__ out) {
  const int t = threadIdx.x;
  double part = 0.0;
  for (int k = t; k < KC; k += 256) {
    double a = (double)avgp[k] / (double)NROWS;
    part += a * log(a + 1e-10);
  }
  __shared__ double sd[256];
  sd[t] = part;
  __syncthreads();
  for (int s = 128; s > 0; s >>= 1) {
    if (t < s) sd[t] += sd[t + s];
    __syncthreads();
  }
  if (t == 0) {
    double H = -sd[0];
    double mse = losssum[0] / (double)((size_t)NROWS * DIM);
    double ccl = 1.25 * mse;
    double sel = -0.1 * H;
    out[OUT_SCAL + 0] = (float)(ccl + sel);
    out[OUT_SCAL + 1] = (float)ccl;
    out[OUT_SCAL + 2] = (float)sel;
  }
}

extern "C" void kernel_launch(void* const* d_in, const int* in_sizes, int n_in,
                              void* d_out, int out_size, void* d_ws, size_t ws_size,
                              hipStream_t stream) {
  const float* z = (const float*)d_in[0];
  const float* cbw = (const float*)d_in[1];
  float* out = (float*)d_out;
  char* ws = (char*)d_ws;
  float* cnorm = (float*)(ws + WS_CNORM);
  float* avgp = (float*)(ws + WS_AVGP);
  double* losssum = (double*)(ws + WS_LOSS);
  float* znorm = (float*)(ws + WS_ZNORM);

  hipMemsetAsync(ws + WS_AVGP, 0, KC * 4, stream);
  hipMemsetAsync(ws + WS_LOSS, 0, 8, stream);
  k_rownorm<<<KC / 256, 256, 0, stream>>>(cbw, cnorm, KC);
  k_rownorm<<<NROWS / 256, 256, 0, stream>>>(z, znorm, NROWS);
  k_main<<<NROWS / BM, 256, 0, stream>>>(z, cbw, cnorm, znorm, out, avgp, losssum);
  k_final<<<1, 256, 0, stream>>>(avgp, losssum, out);
}

// Round 4
// 595.962 us; speedup vs baseline: 5.0820x; 1.2686x over previous
//
#include <hip/hip_runtime.h>
#include <stdint.h>

// Problem: B=8, L=4096, D=256, K=4096
#define NROWS 32768
#define KC 4096
#define DIM 256
#define BM 64             // rows per block
#define BN 128            // codes per k-tile
#define NKT (KC / BN)     // 32
#define NCH 8             // 32-d chunks per k-tile
#define CAP 32
#define MARGIN 3e-4f      // quant band 6.1e-5 + 2*max bf16 score err (~6e-5) + slack

#define OUT_IDX (NROWS * DIM)
#define OUT_SCAL (OUT_IDX + NROWS)

#define WS_CNORM 0
#define WS_AVGP 16384
#define WS_LOSS 32768
#define WS_ZNORM 33024

typedef __bf16 bf8 __attribute__((ext_vector_type(8)));
typedef float f16v __attribute__((ext_vector_type(16)));
struct Chunk { float4 q[4]; };  // 16 floats

// monotonic float<->uint order maps (argmin with first-index tie-break)
__device__ __forceinline__ unsigned ford(float f) {
  unsigned u = __float_as_uint(f);
  return (u & 0x80000000u) ? ~u : (u | 0x80000000u);
}
__device__ __forceinline__ float unford(unsigned u) {
  return __uint_as_float((u & 0x80000000u) ? (u ^ 0x80000000u) : ~u);
}

// numpy pairwise-sum of x**2 (n=256), bitwise-matching np.sum(x**2) (validated R2/R3)
__device__ __forceinline__ float np_rownorm256(const float* __restrict__ p) {
  float h[2];
  #pragma unroll
  for (int half = 0; half < 2; ++half) {
    const float* b = p + half * 128;
    float r[8];
    #pragma unroll
    for (int j = 0; j < 8; ++j) { float v = b[j]; r[j] = __fmul_rn(v, v); }
    for (int i = 8; i < 128; i += 8) {
      #pragma unroll
      for (int j = 0; j < 8; ++j) {
        float v = b[i + j];
        r[j] = __fadd_rn(r[j], __fmul_rn(v, v));
      }
    }
    h[half] = __fadd_rn(
        __fadd_rn(__fadd_rn(r[0], r[1]), __fadd_rn(r[2], r[3])),
        __fadd_rn(__fadd_rn(r[4], r[5]), __fadd_rn(r[6], r[7])));
  }
  return __fadd_rn(h[0], h[1]);
}

__global__ void k_rownorm(const float* __restrict__ x, float* __restrict__ out,
                          int nrows) {
  int r = blockIdx.x * 256 + threadIdx.x;
  if (r < nrows) out[r] = np_rownorm256(x + (size_t)r * DIM);
}

// np-bitwise d2 (validated): sequential fmaf chain d=0..255, then
// d2 = fl(fl(rn+cn) - fl(2*mm))
__device__ __forceinline__ float exact_d2(const float* __restrict__ zr,
                                          const float* __restrict__ cr,
                                          float rn, float cn) {
  float mm = 0.f;
  for (int d = 0; d < DIM; d += 4) {
    float4 zv = *(const float4*)(zr + d);
    float4 cv = *(const float4*)(cr + d);
    mm = __builtin_fmaf(zv.x, cv.x, mm);
    mm = __builtin_fmaf(zv.y, cv.y, mm);
    mm = __builtin_fmaf(zv.z, cv.z, mm);
    mm = __builtin_fmaf(zv.w, cv.w, mm);
  }
  return __fsub_rn(__fadd_rn(rn, cn), __fmul_rn(2.f, mm));
}

// convert 16 staged floats -> 16 bf16, store as two b128 into LDS
__device__ __forceinline__ void cvt_store(__bf16* dst, const Chunk& ck) {
  const float* p = (const float*)&ck;
  bf8 h0, h1;
  #pragma unroll
  for (int j = 0; j < 8; ++j) {
    h0[j] = (__bf16)p[j];
    h1[j] = (__bf16)p[j + 8];
  }
  *(bf8*)(dst) = h0;
  *(bf8*)(dst + 8) = h1;
}

__global__ __launch_bounds__(256, 2) void k_main(
    const float* __restrict__ z, const float* __restrict__ cbw,
    const float* __restrict__ cnorm, const float* __restrict__ znorm,
    float* __restrict__ out, float* __restrict__ avgp,
    double* __restrict__ losssum) {
  // stride 40 shorts (80 B): b128 reads spread uniformly over 32 banks
  __shared__ __bf16 sthi[2][BN][40];           // 20.5 KB, double-buffered
  __shared__ int cand[BM][CAP];
  __shared__ int ccount[BM];
  __shared__ unsigned rowminU[BM];
  __shared__ unsigned long long rowkey[BM];
  __shared__ float esumL[BM], invR[BM], pcolL[BN], lred[256];
  __shared__ int idxr[BM];

  const int t = threadIdx.x;
  const int lane = t & 63, wv = t >> 6;
  const int ln31 = lane & 31, lh = lane >> 5;
  const int rg = wv & 1;        // row group (32 rows)
  const int ch = wv >> 1;       // col half (64 cols of the 128-tile)
  const int row0 = blockIdx.x * BM;
  const int scode = t >> 1;     // staged code (0..127)
  const int shalf = (t & 1) * 16;

  if (t < BM) {
    ccount[t] = 0; rowminU[t] = 0xFFFFFFFFu; esumL[t] = 0.f; rowkey[t] = ~0ULL;
  }

  // ---- A (z rows) register-resident, hi bf16 only ----
  // lane holds z[row0 + rg*32 + ln31][ds*16 + lh*8 + j]
  bf8 Ah[16];
  {
    const float* zp = z + (size_t)(row0 + rg * 32 + ln31) * DIM + lh * 8;
    #pragma unroll
    for (int ds = 0; ds < 16; ++ds) {
      float4 a = *(const float4*)(zp + ds * 16);
      float4 b = *(const float4*)(zp + ds * 16 + 4);
      bf8 h;
      h[0] = (__bf16)a.x; h[1] = (__bf16)a.y; h[2] = (__bf16)a.z; h[3] = (__bf16)a.w;
      h[4] = (__bf16)b.x; h[5] = (__bf16)b.y; h[6] = (__bf16)b.z; h[7] = (__bf16)b.w;
      Ah[ds] = h;
    }
  }
  __syncthreads();

  float rmF[16], es[16];
  #pragma unroll
  for (int i = 0; i < 16; ++i) { rmF[i] = 3.4e38f; es[i] = 0.f; }

  // =================== Phase 1: hi-only 1-MFMA sweep ===================
  for (int kt = 0; kt < NKT; ++kt) {
    const int k0 = kt * BN;
    const float* cbase = cbw + (size_t)(k0 + scode) * DIM + shalf;
    f16v acc[2];
    #pragma unroll
    for (int n = 0; n < 2; ++n)
      #pragma unroll
      for (int r = 0; r < 16; ++r) acc[n][r] = 0.f;

    Chunk pr[2];
    #pragma unroll
    for (int i = 0; i < 4; ++i) pr[0].q[i] = *(const float4*)(cbase + i * 4);
    #pragma unroll
    for (int i = 0; i < 4; ++i) pr[1].q[i] = *(const float4*)(cbase + 32 + i * 4);
    cvt_store(&sthi[0][scode][shalf], pr[0]);  // chunk 0 -> buf 0
    for (int c = 0; c < NCH; ++c) {
      if (c + 2 < NCH) {
        #pragma unroll
        for (int i = 0; i < 4; ++i)
          pr[c & 1].q[i] = *(const float4*)(cbase + (c + 2) * 32 + i * 4);
      }
      __syncthreads();  // all waves done reading buf[(c+1)&1]'s previous tile
      if (c + 1 < NCH)
        cvt_store(&sthi[(c + 1) & 1][scode][shalf], pr[(c + 1) & 1]);
      #pragma unroll
      for (int ds = 0; ds < 2; ++ds) {
        const int dg = c * 2 + ds;
        #pragma unroll
        for (int n = 0; n < 2; ++n) {
          bf8 Bh = *(bf8*)&sthi[c & 1][ch * 64 + n * 32 + ln31][lh * 8 + ds * 16];
          acc[n] = __builtin_amdgcn_mfma_f32_32x32x16_bf16(Ah[dg], Bh, acc[n], 0, 0, 0);
        }
      }
    }
    // ---- scoring: sc = cn - 2*acc (shift-invariant) ----
    #pragma unroll
    for (int n = 0; n < 2; ++n) {
      float cn = cnorm[k0 + ch * 64 + n * 32 + ln31];
      #pragma unroll
      for (int r = 0; r < 16; ++r)
        acc[n][r] = __builtin_fmaf(-2.f, acc[n][r], cn);
    }
    if (kt == 0) {  // prime rowminU so candidate volume stays tiny
      #pragma unroll
      for (int r = 0; r < 16; ++r) {
        float m = fminf(acc[0][r], acc[1][r]);
        rmF[r] = fminf(rmF[r], m);
        int row = (r & 3) + 8 * (r >> 2) + 4 * lh + 32 * rg;
        atomicMin(&rowminU[row], ford(m));
      }
      __syncthreads();
    }
    #pragma unroll
    for (int r = 0; r < 16; ++r) {
      int row = (r & 3) + 8 * (r >> 2) + 4 * lh + 32 * rg;
      rmF[r] = fminf(rmF[r], unford(rowminU[row]));
      float e = es[r];
      #pragma unroll
      for (int n = 0; n < 2; ++n) {
        float sc = acc[n][r];
        e += __expf(-sc);
        if (sc < rmF[r]) { rmF[r] = sc; atomicMin(&rowminU[row], ford(sc)); }
        if (sc <= rmF[r] + MARGIN) {
          int slot = atomicAdd(&ccount[row], 1);
          if (slot < CAP) cand[row][slot] = k0 + ch * 64 + n * 32 + ln31;
        }
      }
      es[r] = e;
    }
  }

  // ---- row softmax sums ----
  #pragma unroll
  for (int r = 0; r < 16; ++r) {
    int row = (r & 3) + 8 * (r >> 2) + 4 * lh + 32 * rg;
    atomicAdd(&esumL[row], es[r]);
  }
  __syncthreads();
  if (t < BM) invR[t] = 1.0f / esumL[t];
  __syncthreads();

  // ---- exact np-bitwise rescore of candidates -> argmin ----
  {
    int r = t & 63, q = t >> 6;   // 4 threads per row
    int cnt = ccount[r];
    const float* zr = z + (size_t)(row0 + r) * DIM;
    float rn = znorm[row0 + r];
    if (cnt <= CAP) {
      for (int s = q; s < cnt; s += 4) {
        int k = cand[r][s];
        float d2 = exact_d2(zr, cbw + (size_t)k * DIM, rn, cnorm[k]);
        atomicMin(&rowkey[r], (((unsigned long long)ford(d2)) << 32) | (unsigned)k);
      }
    } else {  // overflow (improbable): full exact scan, still correct
      for (int k = q; k < KC; k += 4) {
        float d2 = exact_d2(zr, cbw + (size_t)k * DIM, rn, cnorm[k]);
        atomicMin(&rowkey[r], (((unsigned long long)ford(d2)) << 32) | (unsigned)k);
      }
    }
  }
  __syncthreads();
  if (t < BM) {
    int idx = (int)(rowkey[t] & 0xFFFFFFFFULL);
    idxr[t] = idx;
    out[OUT_IDX + row0 + t] = (float)idx;
  }
  __syncthreads();

  // ---- z_q gather, STE output, loss partial ----
  float lacc = 0.f;
  for (int r = 0; r < BM; ++r) {
    int idx = idxr[r];
    float zq = cbw[(size_t)idx * DIM + t];
    float zv = z[(size_t)(row0 + r) * DIM + t];
    float df = __fsub_rn(zq, zv);
    out[(size_t)(row0 + r) * DIM + t] = __fadd_rn(zv, df);
    lacc += df * df;
  }
  lred[t] = lacc;
  __syncthreads();
  #pragma unroll
  for (int s = 128; s > 0; s >>= 1) {
    if (t < s) lred[t] += lred[t + s];
    __syncthreads();
  }
  if (t == 0) atomicAdd(losssum, (double)lred[0]);

  // =================== Phase 2: avg_probs sweep (same structure) ===========
  float ir[16];
  #pragma unroll
  for (int r = 0; r < 16; ++r)
    ir[r] = invR[(r & 3) + 8 * (r >> 2) + 4 * lh + 32 * rg];

  for (int kt = 0; kt < NKT; ++kt) {
    const int k0 = kt * BN;
    const float* cbase = cbw + (size_t)(k0 + scode) * DIM + shalf;
    f16v acc[2];
    #pragma unroll
    for (int n = 0; n < 2; ++n)
      #pragma unroll
      for (int r = 0; r < 16; ++r) acc[n][r] = 0.f;
    if (t < BN) pcolL[t] = 0.f;

    Chunk pr[2];
    #pragma unroll
    for (int i = 0; i < 4; ++i) pr[0].q[i] = *(const float4*)(cbase + i * 4);
    #pragma unroll
    for (int i = 0; i < 4; ++i) pr[1].q[i] = *(const float4*)(cbase + 32 + i * 4);
    cvt_store(&sthi[0][scode][shalf], pr[0]);
    for (int c = 0; c < NCH; ++c) {
      if (c + 2 < NCH) {
        #pragma unroll
        for (int i = 0; i < 4; ++i)
          pr[c & 1].q[i] = *(const float4*)(cbase + (c + 2) * 32 + i * 4);
      }
      __syncthreads();
      if (c + 1 < NCH)
        cvt_store(&sthi[(c + 1) & 1][scode][shalf], pr[(c + 1) & 1]);
      #pragma unroll
      for (int ds = 0; ds < 2; ++ds) {
        const int dg = c * 2 + ds;
        #pragma unroll
        for (int n = 0; n < 2; ++n) {
          bf8 Bh = *(bf8*)&sthi[c & 1][ch * 64 + n * 32 + ln31][lh * 8 + ds * 16];
          acc[n] = __builtin_amdgcn_mfma_f32_32x32x16_bf16(Ah[dg], Bh, acc[n], 0, 0, 0);
        }
      }
    }
    #pragma unroll
    for (int n = 0; n < 2; ++n) {
      float cn = cnorm[k0 + ch * 64 + n * 32 + ln31];
      float s = 0.f;
      #pragma unroll
      for (int r = 0; r < 16; ++r) {
        float sc = __builtin_fmaf(-2.f, acc[n][r], cn);
        s += __expf(-sc) * ir[r];
      }
      s += __shfl_xor(s, 32);  // merge the two row-halves (same col)
      if (lh == 0) atomicAdd(&pcolL[ch * 64 + n * 32 + ln31], s);
    }
    __syncthreads();
    if (t < BN) atomicAdd(&avgp[k0 + t], pcolL[t]);
    __syncthreads();
  }
}

__global__ void k_final(const float* __restrict__ avgp,
                        const double* __restrict__ losssum,
                        float* __restrict__ out) {
  const int t = threadIdx.x;
  double part = 0.0;
  for (int k = t; k < KC; k += 256) {
    double a = (double)avgp[k] / (double)NROWS;
    part += a * log(a + 1e-10);
  }
  __shared__ double sd[256];
  sd[t] = part;
  __syncthreads();
  for (int s = 128; s > 0; s >>= 1) {
    if (t < s) sd[t] += sd[t + s];
    __syncthreads();
  }
  if (t == 0) {
    double H = -sd[0];
    double mse = losssum[0] / (double)((size_t)NROWS * DIM);
    double ccl = 1.25 * mse;
    double sel = -0.1 * H;
    out[OUT_SCAL + 0] = (float)(ccl + sel);
    out[OUT_SCAL + 1] = (float)ccl;
    out[OUT_SCAL + 2] = (float)sel;
  }
}

extern "C" void kernel_launch(void* const* d_in, const int* in_sizes, int n_in,
                              void* d_out, int out_size, void* d_ws, size_t ws_size,
                              hipStream_t stream) {
  const float* z = (const float*)d_in[0];
  const float* cbw = (const float*)d_in[1];
  float* out = (float*)d_out;
  char* ws = (char*)d_ws;
  float* cnorm = (float*)(ws + WS_CNORM);
  float* avgp = (float*)(ws + WS_AVGP);
  double* losssum = (double*)(ws + WS_LOSS);
  float* znorm = (float*)(ws + WS_ZNORM);

  hipMemsetAsync(ws + WS_AVGP, 0, KC * 4, stream);
  hipMemsetAsync(ws + WS_LOSS, 0, 8, stream);
  k_rownorm<<<KC / 256, 256, 0, stream>>>(cbw, cnorm, KC);
  k_rownorm<<<NROWS / 256, 256, 0, stream>>>(z, znorm, NROWS);
  k_main<<<NROWS / BM, 256, 0, stream>>>(z, cbw, cnorm, znorm, out, avgp, losssum);
  k_final<<<1, 256, 0, stream>>>(avgp, losssum, out);
}